// Round 1
// 441.087 us; speedup vs baseline: 1.0368x; 1.0368x over previous
//
#include <hip/hip_runtime.h>

#define N_NODES 100000
#define N_EDGES 3200000
#define R_REL   8
#define C_IN    128
#define HID     64
#define WCOLS   576   // 8 relations * 64 + 64 (root slot)
#define OFFMASK 0x03FFFFFFu

// counting-sort parameters
#define NBUCK 500     // dst buckets
#define NPB   200     // nodes per bucket (500*200 = N)
#define NBLK  1024    // edge chunks
#define CHUNK 3125    // E / NBLK (exact)
#define NCELL (NBUCK * NBLK)   // 512000
#define BCAP  7680    // LDS staging capacity per bucket (mean 6400, sigma ~80)

typedef __attribute__((ext_vector_type(8))) short  short8;
typedef __attribute__((ext_vector_type(4))) float  float4v;

__device__ __forceinline__ float bf2f(unsigned short u) {
    union { unsigned int i; float f; } v; v.i = ((unsigned int)u) << 16; return v.f;
}
__device__ __forceinline__ unsigned short f2bf(float f) {
    union { float f; unsigned int i; } v; v.f = f;
    unsigned int r = v.i + 0x7FFFu + ((v.i >> 16) & 1u);   // RNE
    return (unsigned short)(r >> 16);
}
__device__ __forceinline__ float rl_f(float v, int j) {
    union { float f; int i; } a, b; a.f = v;
    b.i = __builtin_amdgcn_readlane(a.i, j);
    return b.f;
}

// ---------------- weight prep (f32 -> bf16, concatenated+transposed) ----------
__global__ void prep_wcat(const float* __restrict__ W1,
                          const float* __restrict__ root1,
                          const float* __restrict__ W2,
                          const float* __restrict__ root2,
                          unsigned short* __restrict__ BT1,
                          unsigned short* __restrict__ BT2) {
    int idx = blockIdx.x * 256 + threadIdx.x;
    const int T1 = WCOLS * C_IN;          // 73728
    const int T2 = WCOLS * HID;           // 36864
    if (idx < T1) {
        int c = idx / C_IN, k = idx % C_IN;
        float v;
        if (c < 512) { int r = c >> 6, h = c & 63; v = W1[r * (C_IN * 64) + k * 64 + h]; }
        else         { v = root1[k * 64 + (c - 512)]; }
        BT1[idx] = f2bf(v);
    } else if (idx < T1 + T2) {
        int j = idx - T1;
        int c = j / HID, k = j % HID;
        float v;
        if (c < 512) { int r = c >> 6, h = c & 63; v = W2[r * (HID * 64) + k * 64 + h]; }
        else         { v = root2[k * 64 + (c - 512)]; }
        BT2[j] = f2bf(v);
    }
}

// ---------------- K1: per-block LDS counting sort, sequential writes ---------
// esort[blk*CHUNK...] = block's edges sorted by bucket (packed src<<11|dl<<3|rel)
// bcountT[blk*NBUCK+b] = count; lstartT[blk*NBUCK+b] = local exclusive prefix.
__global__ __launch_bounds__(256)
void edge_sort_local(const int* __restrict__ src, const int* __restrict__ dst,
                     const int* __restrict__ et,
                     unsigned int* __restrict__ esort,
                     int* __restrict__ bcountT, int* __restrict__ lstartT) {
    __shared__ int cnt[NBUCK], cur[NBUCK], tsum[256];
    __shared__ unsigned int sedge[CHUNK];
    const int blk = blockIdx.x, tid = threadIdx.x;
    const int e0 = blk * CHUNK;

    for (int i = tid; i < NBUCK; i += 256) cnt[i] = 0;
    __syncthreads();
    for (int i = tid; i < CHUNK; i += 256)
        atomicAdd(&cnt[dst[e0 + i] / NPB], 1);
    __syncthreads();

    // exclusive scan over 500 counters (2 per thread + Hillis-Steele)
    int b0 = tid * 2;
    int s = 0, l1 = 0;
    if (b0 < NBUCK) { s = cnt[b0]; if (b0 + 1 < NBUCK) { l1 = s; s += cnt[b0 + 1]; } }
    tsum[tid] = s; __syncthreads();
    for (int off = 1; off < 256; off <<= 1) {
        int t = (tid >= off) ? tsum[tid - off] : 0;
        __syncthreads(); tsum[tid] += t; __syncthreads();
    }
    int texcl = tsum[tid] - s;
    if (b0 < NBUCK) { cur[b0] = texcl; if (b0 + 1 < NBUCK) cur[b0 + 1] = texcl + l1; }
    __syncthreads();

    for (int b = tid; b < NBUCK; b += 256) {
        bcountT[blk * NBUCK + b] = cnt[b];
        lstartT[blk * NBUCK + b] = cur[b];
    }
    __syncthreads();

    for (int i = tid; i < CHUNK; i += 256) {
        int d = dst[e0 + i];
        int b = d / NPB;
        int pos = atomicAdd(&cur[b], 1);
        sedge[pos] = ((unsigned int)src[e0 + i] << 11) |
                     ((unsigned int)(d - b * NPB) << 3) | (unsigned int)et[e0 + i];
    }
    __syncthreads();
    for (int i = tid; i < CHUNK; i += 256) esort[e0 + i] = sedge[i];
}

// ---------------- bucket totals + scan over 500 buckets ----------------------
__global__ __launch_bounds__(256)
void btot_sum(const int* __restrict__ bcountT, int* __restrict__ btot) {
    __shared__ int tsum[256];
    const int b = blockIdx.x, tid = threadIdx.x;
    int s = 0;
    for (int blk = tid; blk < NBLK; blk += 256) s += bcountT[blk * NBUCK + b];
    tsum[tid] = s; __syncthreads();
    for (int off = 128; off > 0; off >>= 1) {
        if (tid < off) tsum[tid] += tsum[tid + off];
        __syncthreads();
    }
    if (tid == 0) btot[b] = tsum[0];
}

__global__ __launch_bounds__(512)
void scan_btot(int* __restrict__ btot, int nb) {   // nb <= 512, exclusive in place
    __shared__ int tmp[512];
    int tid = threadIdx.x;
    int v = (tid < nb) ? btot[tid] : 0;
    tmp[tid] = v; __syncthreads();
    for (int off = 1; off < 512; off <<= 1) {
        int t = (tid >= off) ? tmp[tid - off] : 0;
        __syncthreads(); tmp[tid] += t; __syncthreads();
    }
    if (tid < nb) btot[tid] = tmp[tid] - v;
}

// ---------------- bucket_build v2: LDS-staged CSR emit -----------------------
// one block per bucket. All per-edge work flat-parallelized:
//   1. scan 1024 run lengths -> rloff[], total
//   2. flat loop (binary search run) reads esort ONCE, stages to LDS, histograms
//   3. scan 1792 (dl,rel) counters -> cur, weights, rowstart
//   4. flat emit into LDS selist/swel (scattered stores stay on-chip)
//   5. coalesced copy-out to global elist/welist
// vs v1: kills the ~9x HBM write amplification (scattered 4B global stores)
// and the serial per-thread run walks.
__global__ __launch_bounds__(256)
void bucket_build(const unsigned int* __restrict__ esort,
                  const int* __restrict__ bcountT, const int* __restrict__ lstartT,
                  const int* __restrict__ btot,
                  unsigned int* __restrict__ elist, float* __restrict__ welist,
                  int* __restrict__ rowstart) {
    __shared__ int   cnt[1792], cur[1792], tsum[256];   // 7168+7168+1024 B
    __shared__ float wt[1600];                          // 6400 B
    __shared__ int   rlen[NBLK], rpos[NBLK], rloff[NBLK]; // 12288 B
    __shared__ unsigned int sedge[BCAP];                // 30720 B
    __shared__ unsigned int selist[BCAP];               // 30720 B
    __shared__ float        swel[BCAP];                 // 30720 B  (total ~126 KB)

    const int b = blockIdx.x, tid = threadIdx.x;
    const int seg0 = btot[b];

    for (int i = tid; i < 1792; i += 256) cnt[i] = 0;
    for (int blk = tid; blk < NBLK; blk += 256) {
        rlen[blk] = bcountT[blk * NBUCK + b];
        rpos[blk] = blk * CHUNK + lstartT[blk * NBUCK + b];
    }
    __syncthreads();

    // ---- scan run lengths: 4/thread + Hillis-Steele over 256 ----
    int rbase = tid * 4;
    int rs = 0, rloc[4];
#pragma unroll
    for (int k = 0; k < 4; ++k) { rloc[k] = rs; rs += rlen[rbase + k]; }
    tsum[tid] = rs; __syncthreads();
    for (int off = 1; off < 256; off <<= 1) {
        int t = (tid >= off) ? tsum[tid - off] : 0;
        __syncthreads(); tsum[tid] += t; __syncthreads();
    }
    int rexcl = tsum[tid] - rs;
#pragma unroll
    for (int k = 0; k < 4; ++k) rloff[rbase + k] = rexcl + rloc[k];
    const int total = tsum[255];            // bucket edge count
    __syncthreads();
    const bool fits = (total <= BCAP);      // safety fallback (mean 6400, 16 sigma margin)

    // ---- pass 1: flat stage + histogram (esort read once) ----
    for (int i = tid; i < total; i += 256) {
        int lo = 0, hi = NBLK - 1;          // largest blk with rloff[blk] <= i
        while (lo < hi) { int mid = (lo + hi + 1) >> 1; if (rloff[mid] <= i) lo = mid; else hi = mid - 1; }
        unsigned int e = esort[rpos[lo] + (i - rloff[lo])];
        if (fits) sedge[i] = e;
        atomicAdd(&cnt[(int)((e >> 3) & 255u) * 8 + (int)(e & 7u)], 1);
    }
    __syncthreads();

    // ---- exclusive scan over 1792 counters: 7/thread + Hillis-Steele ----
    int base = tid * 7, s = 0, loc[7];
#pragma unroll
    for (int k = 0; k < 7; ++k) { loc[k] = s; s += cnt[base + k]; }
    tsum[tid] = s; __syncthreads();
    for (int off = 1; off < 256; off <<= 1) {
        int t = (tid >= off) ? tsum[tid - off] : 0;
        __syncthreads(); tsum[tid] += t; __syncthreads();
    }
    int texcl = tsum[tid] - s;
#pragma unroll
    for (int k = 0; k < 7; ++k) cur[base + k] = texcl + loc[k];
    __syncthreads();

    for (int j = tid; j < 1600; j += 256) {
        int c = cnt[j];
        wt[j] = 1.0f / (float)(c > 1 ? c : 1);
    }
    if (tid < NPB) rowstart[b * NPB + tid] = seg0 + cur[tid * 8];
    if (b == NBUCK - 1 && tid == 0) rowstart[N_NODES] = N_EDGES;
    __syncthreads();

    // ---- pass 2: flat emit into LDS (scatter stays on-chip) ----
    for (int i = tid; i < total; i += 256) {
        unsigned int e;
        if (fits) e = sedge[i];
        else {
            int lo = 0, hi = NBLK - 1;
            while (lo < hi) { int mid = (lo + hi + 1) >> 1; if (rloff[mid] <= i) lo = mid; else hi = mid - 1; }
            e = esort[rpos[lo] + (i - rloff[lo])];
        }
        int r = (int)(e & 7u);
        int j = (int)((e >> 3) & 255u) * 8 + r;
        int p = atomicAdd(&cur[j], 1);
        unsigned int eo = (e >> 11) * WCOLS + (unsigned int)(r * 64);
        float w = wt[j];
        if (fits) { selist[p] = eo; swel[p] = w; }
        else      { elist[seg0 + p] = eo; welist[seg0 + p] = w; }
    }
    __syncthreads();

    // ---- coalesced copy-out ----
    if (fits) {
        for (int i = tid; i < total; i += 256) {
            elist[seg0 + i]  = selist[i];
            welist[seg0 + i] = swel[i];
        }
    }
}

// ---------------- GEMM: Out[N][576] (bf16) = A[N][K] @ Wcat ------------------
template <int K, bool AF32>
__global__ __launch_bounds__(256)
void gemm_rows(const void* __restrict__ Araw,
               const unsigned short* __restrict__ BT,
               unsigned short* __restrict__ Out, int nrows) {
    constexpr int KSTEPS = K / 32;
    constexpr int LDB = K + 8;
    __shared__ __align__(16) unsigned short Blds[64 * LDB];
    __shared__ __align__(16) unsigned short stage[4][16 * 64];

    const int wave = threadIdx.x >> 6;
    const int lane = threadIdx.x & 63;
    const int l15 = lane & 15, quad = lane >> 4;
    const int rowbase = blockIdx.x * 64 + wave * 16;
    int arow = rowbase + l15;
    if (arow >= nrows) arow = nrows - 1;

    short8 afrag[KSTEPS];
    if constexpr (AF32) {
        const float* Af = (const float*)Araw;
#pragma unroll
        for (int ks = 0; ks < KSTEPS; ++ks) {
            const float* p = Af + (size_t)arow * K + ks * 32 + quad * 8;
            float4v u0 = *(const float4v*)p;
            float4v u1 = *(const float4v*)(p + 4);
            short8 f;
            f[0] = (short)f2bf(u0[0]); f[1] = (short)f2bf(u0[1]);
            f[2] = (short)f2bf(u0[2]); f[3] = (short)f2bf(u0[3]);
            f[4] = (short)f2bf(u1[0]); f[5] = (short)f2bf(u1[1]);
            f[6] = (short)f2bf(u1[2]); f[7] = (short)f2bf(u1[3]);
            afrag[ks] = f;
        }
    } else {
        const unsigned short* Ab = (const unsigned short*)Araw;
#pragma unroll
        for (int ks = 0; ks < KSTEPS; ++ks)
            afrag[ks] = *(const short8*)(Ab + (size_t)arow * K + ks * 32 + quad * 8);
    }

    for (int chunk = 0; chunk < 9; ++chunk) {
        __syncthreads();
        {
            const unsigned short* src = BT + (size_t)chunk * 64 * K;
            const int nvec = 64 * K / 8;
            for (int i = threadIdx.x; i < nvec; i += 256) {
                int r = i / (K / 8);
                int cpos = (i % (K / 8)) * 8;
                *(uint4*)(&Blds[r * LDB + cpos]) = *(const uint4*)(src + r * K + cpos);
            }
        }
        __syncthreads();

        float4v acc[4];
#pragma unroll
        for (int ct = 0; ct < 4; ++ct) { acc[ct][0] = 0.f; acc[ct][1] = 0.f; acc[ct][2] = 0.f; acc[ct][3] = 0.f; }

#pragma unroll
        for (int ct = 0; ct < 4; ++ct) {
#pragma unroll
            for (int ks = 0; ks < KSTEPS; ++ks) {
                short8 bfrag = *(const short8*)(&Blds[(ct * 16 + l15) * LDB + ks * 32 + quad * 8]);
                acc[ct] = __builtin_amdgcn_mfma_f32_16x16x32_bf16(afrag[ks], bfrag, acc[ct], 0, 0, 0);
            }
        }

#pragma unroll
        for (int ct = 0; ct < 4; ++ct)
#pragma unroll
            for (int r = 0; r < 4; ++r)
                stage[wave][(quad * 4 + r) * 64 + ct * 16 + l15] = f2bf(acc[ct][r]);
        __syncthreads();

        {
            int r = lane >> 2, j = lane & 3;
            int orow = rowbase + r;
            if (orow < nrows) {
#pragma unroll
                for (int p = 0; p < 2; ++p) {
                    int c0 = (j + p * 4) * 8;
                    uint4 v = *(const uint4*)&stage[wave][r * 64 + c0];
                    *(uint4*)(Out + (size_t)orow * WCOLS + chunk * 64 + c0) = v;
                }
            }
        }
    }
}

// ---------------- fused CSR aggregate + root + bias (+relu) ------------------
// one wave per node, lane = channel. 16-deep explicit gather pipeline.
template <int MODE>   // 0: relu -> bf16 h ; 1: -> f32 out
__global__ __launch_bounds__(256)
void agg_fused(const unsigned short* __restrict__ XW,
               const unsigned int* __restrict__ elist,
               const float* __restrict__ welist,
               const int* __restrict__ rowstart,
               const float* __restrict__ bias,
               void* __restrict__ outp) {
    const int wave = threadIdx.x >> 6, lane = threadIdx.x & 63;
    const int n = blockIdx.x * 4 + wave;          // grid covers N exactly
    const int beg = rowstart[n], end = rowstart[n + 1];

    const unsigned short* XWl = XW + lane;        // fold lane offset into base

    float acc = 0.f;
    int i = beg;
    while (i < end) {
        int m = end - i; if (m > 64) m = 64;
        int idx = i + lane; if (idx >= end) idx = end - 1;
        unsigned int ub = elist[idx];             // one coalesced load / 64 edges
        float        wb = welist[idx];

        int j = 0;
        for (; j + 16 <= m; j += 16) {
            float vv[16], ww[16];
#pragma unroll
            for (int t = 0; t < 16; ++t) {
                unsigned int u = (unsigned int)__builtin_amdgcn_readlane((int)ub, j + t) & OFFMASK;
                ww[t] = rl_f(wb, j + t);
                vv[t] = bf2f(XWl[u]);
            }
#pragma unroll
            for (int t = 0; t < 16; ++t) acc += ww[t] * vv[t];
        }
        for (; j + 4 <= m; j += 4) {
            float vv[4], ww[4];
#pragma unroll
            for (int t = 0; t < 4; ++t) {
                unsigned int u = (unsigned int)__builtin_amdgcn_readlane((int)ub, j + t) & OFFMASK;
                ww[t] = rl_f(wb, j + t);
                vv[t] = bf2f(XWl[u]);
            }
#pragma unroll
            for (int t = 0; t < 4; ++t) acc += ww[t] * vv[t];
        }
        for (; j < m; ++j) {
            unsigned int u = (unsigned int)__builtin_amdgcn_readlane((int)ub, j) & OFFMASK;
            float w = rl_f(wb, j);
            acc += w * bf2f(XWl[u]);
        }
        i += m;
    }

    float res = acc + bf2f(XW[(size_t)n * WCOLS + 512 + lane]) + bias[lane];
    if (MODE == 0) {
        res = res > 0.f ? res : 0.f;
        ((unsigned short*)outp)[(size_t)n * 64 + lane] = f2bf(res);
    } else {
        ((float*)outp)[(size_t)n * 64 + lane] = res;
    }
}

// ---------------- launch ------------------------------------------------------
extern "C" void kernel_launch(void* const* d_in, const int* in_sizes, int n_in,
                              void* d_out, int out_size, void* d_ws, size_t ws_size,
                              hipStream_t stream) {
    const float* x     = (const float*)d_in[0];
    const int*   eidx  = (const int*)d_in[1];
    const int*   etyp  = (const int*)d_in[2];
    const float* W1    = (const float*)d_in[3];
    const float* root1 = (const float*)d_in[4];
    const float* b1    = (const float*)d_in[5];
    const float* W2    = (const float*)d_in[6];
    const float* root2 = (const float*)d_in[7];
    const float* b2    = (const float*)d_in[8];
    float*       out   = (float*)d_out;

    char* ws = (char*)d_ws;
    size_t off = 0;
    auto alloc = [&](size_t bytes) { char* p = ws + off; off += (bytes + 255) & ~(size_t)255; return p; };

    unsigned short* xW       = (unsigned short*)alloc((size_t)N_NODES * WCOLS * 2); // 115.2 MB (reused as hW)
    unsigned short* h        = (unsigned short*)alloc((size_t)N_NODES * HID * 2);   //  12.8 MB
    unsigned int*   elist    = (unsigned int*)alloc((size_t)N_EDGES * 4);           //  12.8 MB
    float*          welist   = (float*)alloc((size_t)N_EDGES * 4);                  //  12.8 MB
    int*            rowstart = (int*)alloc((size_t)(N_NODES + 1) * 4);              //   0.4 MB
    unsigned short* BT1      = (unsigned short*)alloc((size_t)WCOLS * C_IN * 2);
    unsigned short* BT2      = (unsigned short*)alloc((size_t)WCOLS * HID * 2);
    // total ~154.4 MB

    // sort scratch aliases into xW (dead before gemm1 writes xW)
    unsigned int* esort   = (unsigned int*)xW;                          // 12.8 MB
    int*          bcountT = (int*)((char*)xW + (size_t)N_EDGES * 4);    //  2.05 MB
    int*          lstartT = bcountT + NCELL;                            //  2.05 MB
    int*          btot    = lstartT + NCELL;                            //  2 KB

    const int* srcp = eidx;
    const int* dstp = eidx + N_EDGES;

    prep_wcat<<<(WCOLS * (C_IN + HID) + 255) / 256, 256, 0, stream>>>(W1, root1, W2, root2, BT1, BT2);

    // CSR build — sequential-write sort + fused per-bucket CSR emit
    edge_sort_local<<<NBLK, 256, 0, stream>>>(srcp, dstp, etyp, esort, bcountT, lstartT);
    btot_sum<<<NBUCK, 256, 0, stream>>>(bcountT, btot);
    scan_btot<<<1, 512, 0, stream>>>(btot, NBUCK);
    bucket_build<<<NBUCK, 256, 0, stream>>>(esort, bcountT, lstartT, btot, elist, welist, rowstart);

    const int gemm_grid = (N_NODES + 63) / 64;    // 1563
    const int agg_grid  = N_NODES / 4;            // 25000

    // layer 1: x (f32) -> xW (bf16) -> h (bf16, relu)
    gemm_rows<C_IN, true><<<gemm_grid, 256, 0, stream>>>((const void*)x, BT1, xW, N_NODES);
    agg_fused<0><<<agg_grid, 256, 0, stream>>>(xW, elist, welist, rowstart, b1, (void*)h);

    // layer 2: h -> hW (reuse xW) -> out (f32)
    gemm_rows<HID, false><<<gemm_grid, 256, 0, stream>>>((const void*)h, BT2, xW, N_NODES);
    agg_fused<1><<<agg_grid, 256, 0, stream>>>(xW, elist, welist, rowstart, b2, (void*)out);
}

// Round 2
// 415.022 us; speedup vs baseline: 1.1019x; 1.0628x over previous
//
#include <hip/hip_runtime.h>

#define N_NODES 100000
#define N_EDGES 3200000
#define R_REL   8
#define C_IN    128
#define HID     64
#define WCOLS   576   // 8 relations * 64 + 64 (root slot)
#define OFFMASK 0x03FFFFFFu

// counting-sort parameters
#define NBUCK 500     // dst buckets
#define NPB   200     // nodes per bucket (500*200 = N)
#define NBLK  256     // edge chunks (long runs: CHUNK/NBUCK = 25 edges = 100 B)
#define CHUNK 12500   // E / NBLK (exact)
#define NCELL (NBUCK * NBLK)   // 128000
#define BCAP  7680    // LDS staging capacity per bucket (mean 6400, sigma ~80)

typedef __attribute__((ext_vector_type(8))) short  short8;
typedef __attribute__((ext_vector_type(4))) float  float4v;

__device__ __forceinline__ float bf2f(unsigned short u) {
    union { unsigned int i; float f; } v; v.i = ((unsigned int)u) << 16; return v.f;
}
__device__ __forceinline__ unsigned short f2bf(float f) {
    union { float f; unsigned int i; } v; v.f = f;
    unsigned int r = v.i + 0x7FFFu + ((v.i >> 16) & 1u);   // RNE
    return (unsigned short)(r >> 16);
}
__device__ __forceinline__ float rl_f(float v, int j) {
    union { float f; int i; } a, b; a.f = v;
    b.i = __builtin_amdgcn_readlane(a.i, j);
    return b.f;
}

// ---------------- weight prep (f32 -> bf16, concatenated+transposed) ----------
__global__ void prep_wcat(const float* __restrict__ W1,
                          const float* __restrict__ root1,
                          const float* __restrict__ W2,
                          const float* __restrict__ root2,
                          unsigned short* __restrict__ BT1,
                          unsigned short* __restrict__ BT2) {
    int idx = blockIdx.x * 256 + threadIdx.x;
    const int T1 = WCOLS * C_IN;          // 73728
    const int T2 = WCOLS * HID;           // 36864
    if (idx < T1) {
        int c = idx / C_IN, k = idx % C_IN;
        float v;
        if (c < 512) { int r = c >> 6, h = c & 63; v = W1[r * (C_IN * 64) + k * 64 + h]; }
        else         { v = root1[k * 64 + (c - 512)]; }
        BT1[idx] = f2bf(v);
    } else if (idx < T1 + T2) {
        int j = idx - T1;
        int c = j / HID, k = j % HID;
        float v;
        if (c < 512) { int r = c >> 6, h = c & 63; v = W2[r * (HID * 64) + k * 64 + h]; }
        else         { v = root2[k * 64 + (c - 512)]; }
        BT2[j] = f2bf(v);
    }
}

// ---------------- K1: per-block LDS counting sort, sequential writes ---------
// esort[blk*CHUNK...] = block's edges sorted by bucket (packed src<<11|dl<<3|rel)
// bcountT[blk*NBUCK+b] = count; lstartT[blk*NBUCK+b] = local exclusive prefix.
// 512 threads; CHUNK=12500 gives 25-edge (100 B) runs for coalesced gathers
// downstream in bucket_build.
__global__ __launch_bounds__(512)
void edge_sort_local(const int* __restrict__ src, const int* __restrict__ dst,
                     const int* __restrict__ et,
                     unsigned int* __restrict__ esort,
                     int* __restrict__ bcountT, int* __restrict__ lstartT) {
    __shared__ int cnt[NBUCK], cur[NBUCK], tsum[512];
    __shared__ unsigned int sedge[CHUNK];               // 50 KB
    const int blk = blockIdx.x, tid = threadIdx.x;
    const int e0 = blk * CHUNK;

    for (int i = tid; i < NBUCK; i += 512) cnt[i] = 0;
    __syncthreads();
    for (int i = tid; i < CHUNK; i += 512)
        atomicAdd(&cnt[dst[e0 + i] / NPB], 1);
    __syncthreads();

    // exclusive scan over 500 counters (1 per thread, Hillis-Steele over 512)
    int v = (tid < NBUCK) ? cnt[tid] : 0;
    tsum[tid] = v; __syncthreads();
    for (int off = 1; off < 512; off <<= 1) {
        int t = (tid >= off) ? tsum[tid - off] : 0;
        __syncthreads(); tsum[tid] += t; __syncthreads();
    }
    if (tid < NBUCK) cur[tid] = tsum[tid] - v;
    __syncthreads();

    for (int b = tid; b < NBUCK; b += 512) {
        bcountT[blk * NBUCK + b] = cnt[b];
        lstartT[blk * NBUCK + b] = cur[b];
    }
    __syncthreads();

    for (int i = tid; i < CHUNK; i += 512) {
        int d = dst[e0 + i];
        int b = d / NPB;
        int pos = atomicAdd(&cur[b], 1);
        sedge[pos] = ((unsigned int)src[e0 + i] << 11) |
                     ((unsigned int)(d - b * NPB) << 3) | (unsigned int)et[e0 + i];
    }
    __syncthreads();
    for (int i = tid; i < CHUNK; i += 512) esort[e0 + i] = sedge[i];
}

// ---------------- bucket totals + scan over 500 buckets ----------------------
__global__ __launch_bounds__(256)
void btot_sum(const int* __restrict__ bcountT, int* __restrict__ btot) {
    __shared__ int tsum[256];
    const int b = blockIdx.x, tid = threadIdx.x;
    int s = 0;
    for (int blk = tid; blk < NBLK; blk += 256) s += bcountT[blk * NBUCK + b];
    tsum[tid] = s; __syncthreads();
    for (int off = 128; off > 0; off >>= 1) {
        if (tid < off) tsum[tid] += tsum[tid + off];
        __syncthreads();
    }
    if (tid == 0) btot[b] = tsum[0];
}

__global__ __launch_bounds__(512)
void scan_btot(int* __restrict__ btot, int nb) {   // nb <= 512, exclusive in place
    __shared__ int tmp[512];
    int tid = threadIdx.x;
    int v = (tid < nb) ? btot[tid] : 0;
    tmp[tid] = v; __syncthreads();
    for (int off = 1; off < 512; off <<= 1) {
        int t = (tid >= off) ? tmp[tid - off] : 0;
        __syncthreads(); tmp[tid] += t; __syncthreads();
    }
    if (tid < nb) btot[tid] = tmp[tid] - v;
}

// ---------------- bucket_build v3: LDS-staged CSR emit, 512 thr --------------
// one block per bucket. All per-edge work flat-parallelized:
//   1. scan 256 run lengths -> rloff[], total
//   2. flat loop (8-step binary search) reads esort ONCE (25-edge coalesced
//      runs), stages to LDS, histograms
//   3. scan (dl,rel) counters -> cur, weights, rowstart
//   4. flat emit into LDS selist/swel (scattered stores stay on-chip)
//   5. coalesced copy-out to global elist/welist
// v2->v3: 512 threads (8 waves/CU vs 4), NBLK 1024->256 (4x longer runs ->
// ~1.6x instead of ~5x fetch amplification; 8 vs 10 search steps; 3 KB vs
// 12 KB run tables).
__global__ __launch_bounds__(512)
void bucket_build(const unsigned int* __restrict__ esort,
                  const int* __restrict__ bcountT, const int* __restrict__ lstartT,
                  const int* __restrict__ btot,
                  unsigned int* __restrict__ elist, float* __restrict__ welist,
                  int* __restrict__ rowstart) {
    __shared__ int   cnt[2048], cur[2048], tsum[512];   // 8192+8192+2048 B
    __shared__ float wt[1600];                          // 6400 B
    __shared__ int   rlen[NBLK], rpos[NBLK], rloff[NBLK]; // 3072 B
    __shared__ unsigned int sedge[BCAP];                // 30720 B
    __shared__ unsigned int selist[BCAP];               // 30720 B
    __shared__ float        swel[BCAP];                 // 30720 B  (total ~117 KB)

    const int b = blockIdx.x, tid = threadIdx.x;
    const int seg0 = btot[b];

    for (int i = tid; i < 2048; i += 512) cnt[i] = 0;
    if (tid < NBLK) {
        rlen[tid] = bcountT[tid * NBUCK + b];
        rpos[tid] = tid * CHUNK + lstartT[tid * NBUCK + b];
    }
    __syncthreads();

    // ---- scan run lengths (1 run/thread, Hillis-Steele over 512) ----
    int rv = (tid < NBLK) ? rlen[tid] : 0;
    tsum[tid] = rv; __syncthreads();
    for (int off = 1; off < 512; off <<= 1) {
        int t = (tid >= off) ? tsum[tid - off] : 0;
        __syncthreads(); tsum[tid] += t; __syncthreads();
    }
    if (tid < NBLK) rloff[tid] = tsum[tid] - rv;
    const int total = tsum[NBLK - 1];       // bucket edge count
    __syncthreads();
    const bool fits = (total <= BCAP);      // safety fallback (mean 6400, 16 sigma margin)

    // ---- pass 1: flat stage + histogram (esort read once) ----
    for (int i = tid; i < total; i += 512) {
        int lo = 0, hi = NBLK - 1;          // largest blk with rloff[blk] <= i
        while (lo < hi) { int mid = (lo + hi + 1) >> 1; if (rloff[mid] <= i) lo = mid; else hi = mid - 1; }
        unsigned int e = esort[rpos[lo] + (i - rloff[lo])];
        if (fits) sedge[i] = e;
        atomicAdd(&cnt[(int)((e >> 3) & 255u) * 8 + (int)(e & 7u)], 1);
    }
    __syncthreads();

    // ---- exclusive scan over 2048 counters: 4/thread + Hillis-Steele ----
    int base = tid * 4, s = 0, loc[4];
#pragma unroll
    for (int k = 0; k < 4; ++k) { loc[k] = s; s += cnt[base + k]; }
    tsum[tid] = s; __syncthreads();
    for (int off = 1; off < 512; off <<= 1) {
        int t = (tid >= off) ? tsum[tid - off] : 0;
        __syncthreads(); tsum[tid] += t; __syncthreads();
    }
    int texcl = tsum[tid] - s;
#pragma unroll
    for (int k = 0; k < 4; ++k) cur[base + k] = texcl + loc[k];
    __syncthreads();

    for (int j = tid; j < 1600; j += 512) {
        int c = cnt[j];
        wt[j] = 1.0f / (float)(c > 1 ? c : 1);
    }
    if (tid < NPB) rowstart[b * NPB + tid] = seg0 + cur[tid * 8];
    if (b == NBUCK - 1 && tid == 0) rowstart[N_NODES] = N_EDGES;
    __syncthreads();

    // ---- pass 2: flat emit into LDS (scatter stays on-chip) ----
    for (int i = tid; i < total; i += 512) {
        unsigned int e;
        if (fits) e = sedge[i];
        else {
            int lo = 0, hi = NBLK - 1;
            while (lo < hi) { int mid = (lo + hi + 1) >> 1; if (rloff[mid] <= i) lo = mid; else hi = mid - 1; }
            e = esort[rpos[lo] + (i - rloff[lo])];
        }
        int r = (int)(e & 7u);
        int j = (int)((e >> 3) & 255u) * 8 + r;
        int p = atomicAdd(&cur[j], 1);
        unsigned int eo = (e >> 11) * WCOLS + (unsigned int)(r * 64);
        float w = wt[j];
        if (fits) { selist[p] = eo; swel[p] = w; }
        else      { elist[seg0 + p] = eo; welist[seg0 + p] = w; }
    }
    __syncthreads();

    // ---- coalesced copy-out ----
    if (fits) {
        for (int i = tid; i < total; i += 512) {
            elist[seg0 + i]  = selist[i];
            welist[seg0 + i] = swel[i];
        }
    }
}

// ---------------- GEMM: Out[N][576] (bf16) = A[N][K] @ Wcat ------------------
template <int K, bool AF32>
__global__ __launch_bounds__(256)
void gemm_rows(const void* __restrict__ Araw,
               const unsigned short* __restrict__ BT,
               unsigned short* __restrict__ Out, int nrows) {
    constexpr int KSTEPS = K / 32;
    constexpr int LDB = K + 8;
    __shared__ __align__(16) unsigned short Blds[64 * LDB];
    __shared__ __align__(16) unsigned short stage[4][16 * 64];

    const int wave = threadIdx.x >> 6;
    const int lane = threadIdx.x & 63;
    const int l15 = lane & 15, quad = lane >> 4;
    const int rowbase = blockIdx.x * 64 + wave * 16;
    int arow = rowbase + l15;
    if (arow >= nrows) arow = nrows - 1;

    short8 afrag[KSTEPS];
    if constexpr (AF32) {
        const float* Af = (const float*)Araw;
#pragma unroll
        for (int ks = 0; ks < KSTEPS; ++ks) {
            const float* p = Af + (size_t)arow * K + ks * 32 + quad * 8;
            float4v u0 = *(const float4v*)p;
            float4v u1 = *(const float4v*)(p + 4);
            short8 f;
            f[0] = (short)f2bf(u0[0]); f[1] = (short)f2bf(u0[1]);
            f[2] = (short)f2bf(u0[2]); f[3] = (short)f2bf(u0[3]);
            f[4] = (short)f2bf(u1[0]); f[5] = (short)f2bf(u1[1]);
            f[6] = (short)f2bf(u1[2]); f[7] = (short)f2bf(u1[3]);
            afrag[ks] = f;
        }
    } else {
        const unsigned short* Ab = (const unsigned short*)Araw;
#pragma unroll
        for (int ks = 0; ks < KSTEPS; ++ks)
            afrag[ks] = *(const short8*)(Ab + (size_t)arow * K + ks * 32 + quad * 8);
    }

    for (int chunk = 0; chunk < 9; ++chunk) {
        __syncthreads();
        {
            const unsigned short* src = BT + (size_t)chunk * 64 * K;
            const int nvec = 64 * K / 8;
            for (int i = threadIdx.x; i < nvec; i += 256) {
                int r = i / (K / 8);
                int cpos = (i % (K / 8)) * 8;
                *(uint4*)(&Blds[r * LDB + cpos]) = *(const uint4*)(src + r * K + cpos);
            }
        }
        __syncthreads();

        float4v acc[4];
#pragma unroll
        for (int ct = 0; ct < 4; ++ct) { acc[ct][0] = 0.f; acc[ct][1] = 0.f; acc[ct][2] = 0.f; acc[ct][3] = 0.f; }

#pragma unroll
        for (int ct = 0; ct < 4; ++ct) {
#pragma unroll
            for (int ks = 0; ks < KSTEPS; ++ks) {
                short8 bfrag = *(const short8*)(&Blds[(ct * 16 + l15) * LDB + ks * 32 + quad * 8]);
                acc[ct] = __builtin_amdgcn_mfma_f32_16x16x32_bf16(afrag[ks], bfrag, acc[ct], 0, 0, 0);
            }
        }

#pragma unroll
        for (int ct = 0; ct < 4; ++ct)
#pragma unroll
            for (int r = 0; r < 4; ++r)
                stage[wave][(quad * 4 + r) * 64 + ct * 16 + l15] = f2bf(acc[ct][r]);
        __syncthreads();

        {
            int r = lane >> 2, j = lane & 3;
            int orow = rowbase + r;
            if (orow < nrows) {
#pragma unroll
                for (int p = 0; p < 2; ++p) {
                    int c0 = (j + p * 4) * 8;
                    uint4 v = *(const uint4*)&stage[wave][r * 64 + c0];
                    *(uint4*)(Out + (size_t)orow * WCOLS + chunk * 64 + c0) = v;
                }
            }
        }
    }
}

// ---------------- fused CSR aggregate + root + bias (+relu) ------------------
// one wave per node, lane = channel. 16-deep explicit gather pipeline.
template <int MODE>   // 0: relu -> bf16 h ; 1: -> f32 out
__global__ __launch_bounds__(256)
void agg_fused(const unsigned short* __restrict__ XW,
               const unsigned int* __restrict__ elist,
               const float* __restrict__ welist,
               const int* __restrict__ rowstart,
               const float* __restrict__ bias,
               void* __restrict__ outp) {
    const int wave = threadIdx.x >> 6, lane = threadIdx.x & 63;
    const int n = blockIdx.x * 4 + wave;          // grid covers N exactly
    const int beg = rowstart[n], end = rowstart[n + 1];

    const unsigned short* XWl = XW + lane;        // fold lane offset into base

    float acc = 0.f;
    int i = beg;
    while (i < end) {
        int m = end - i; if (m > 64) m = 64;
        int idx = i + lane; if (idx >= end) idx = end - 1;
        unsigned int ub = elist[idx];             // one coalesced load / 64 edges
        float        wb = welist[idx];

        int j = 0;
        for (; j + 16 <= m; j += 16) {
            float vv[16], ww[16];
#pragma unroll
            for (int t = 0; t < 16; ++t) {
                unsigned int u = (unsigned int)__builtin_amdgcn_readlane((int)ub, j + t) & OFFMASK;
                ww[t] = rl_f(wb, j + t);
                vv[t] = bf2f(XWl[u]);
            }
#pragma unroll
            for (int t = 0; t < 16; ++t) acc += ww[t] * vv[t];
        }
        for (; j + 4 <= m; j += 4) {
            float vv[4], ww[4];
#pragma unroll
            for (int t = 0; t < 4; ++t) {
                unsigned int u = (unsigned int)__builtin_amdgcn_readlane((int)ub, j + t) & OFFMASK;
                ww[t] = rl_f(wb, j + t);
                vv[t] = bf2f(XWl[u]);
            }
#pragma unroll
            for (int t = 0; t < 4; ++t) acc += ww[t] * vv[t];
        }
        for (; j < m; ++j) {
            unsigned int u = (unsigned int)__builtin_amdgcn_readlane((int)ub, j) & OFFMASK;
            float w = rl_f(wb, j);
            acc += w * bf2f(XWl[u]);
        }
        i += m;
    }

    float res = acc + bf2f(XW[(size_t)n * WCOLS + 512 + lane]) + bias[lane];
    if (MODE == 0) {
        res = res > 0.f ? res : 0.f;
        ((unsigned short*)outp)[(size_t)n * 64 + lane] = f2bf(res);
    } else {
        ((float*)outp)[(size_t)n * 64 + lane] = res;
    }
}

// ---------------- launch ------------------------------------------------------
extern "C" void kernel_launch(void* const* d_in, const int* in_sizes, int n_in,
                              void* d_out, int out_size, void* d_ws, size_t ws_size,
                              hipStream_t stream) {
    const float* x     = (const float*)d_in[0];
    const int*   eidx  = (const int*)d_in[1];
    const int*   etyp  = (const int*)d_in[2];
    const float* W1    = (const float*)d_in[3];
    const float* root1 = (const float*)d_in[4];
    const float* b1    = (const float*)d_in[5];
    const float* W2    = (const float*)d_in[6];
    const float* root2 = (const float*)d_in[7];
    const float* b2    = (const float*)d_in[8];
    float*       out   = (float*)d_out;

    char* ws = (char*)d_ws;
    size_t off = 0;
    auto alloc = [&](size_t bytes) { char* p = ws + off; off += (bytes + 255) & ~(size_t)255; return p; };

    unsigned short* xW       = (unsigned short*)alloc((size_t)N_NODES * WCOLS * 2); // 115.2 MB (reused as hW)
    unsigned short* h        = (unsigned short*)alloc((size_t)N_NODES * HID * 2);   //  12.8 MB
    unsigned int*   elist    = (unsigned int*)alloc((size_t)N_EDGES * 4);           //  12.8 MB
    float*          welist   = (float*)alloc((size_t)N_EDGES * 4);                  //  12.8 MB
    int*            rowstart = (int*)alloc((size_t)(N_NODES + 1) * 4);              //   0.4 MB
    unsigned short* BT1      = (unsigned short*)alloc((size_t)WCOLS * C_IN * 2);
    unsigned short* BT2      = (unsigned short*)alloc((size_t)WCOLS * HID * 2);
    // total ~154.4 MB

    // sort scratch aliases into xW (dead before gemm1 writes xW)
    unsigned int* esort   = (unsigned int*)xW;                          // 12.8 MB
    int*          bcountT = (int*)((char*)xW + (size_t)N_EDGES * 4);    //  0.5 MB
    int*          lstartT = bcountT + NCELL;                            //  0.5 MB
    int*          btot    = lstartT + NCELL;                            //  2 KB

    const int* srcp = eidx;
    const int* dstp = eidx + N_EDGES;

    prep_wcat<<<(WCOLS * (C_IN + HID) + 255) / 256, 256, 0, stream>>>(W1, root1, W2, root2, BT1, BT2);

    // CSR build — sequential-write sort + fused per-bucket CSR emit
    edge_sort_local<<<NBLK, 512, 0, stream>>>(srcp, dstp, etyp, esort, bcountT, lstartT);
    btot_sum<<<NBUCK, 256, 0, stream>>>(bcountT, btot);
    scan_btot<<<1, 512, 0, stream>>>(btot, NBUCK);
    bucket_build<<<NBUCK, 512, 0, stream>>>(esort, bcountT, lstartT, btot, elist, welist, rowstart);

    const int gemm_grid = (N_NODES + 63) / 64;    // 1563
    const int agg_grid  = N_NODES / 4;            // 25000

    // layer 1: x (f32) -> xW (bf16) -> h (bf16, relu)
    gemm_rows<C_IN, true><<<gemm_grid, 256, 0, stream>>>((const void*)x, BT1, xW, N_NODES);
    agg_fused<0><<<agg_grid, 256, 0, stream>>>(xW, elist, welist, rowstart, b1, (void*)h);

    // layer 2: h -> hW (reuse xW) -> out (f32)
    gemm_rows<HID, false><<<gemm_grid, 256, 0, stream>>>((const void*)h, BT2, xW, N_NODES);
    agg_fused<1><<<agg_grid, 256, 0, stream>>>(xW, elist, welist, rowstart, b2, (void*)out);
}

// Round 3
// 412.081 us; speedup vs baseline: 1.1098x; 1.0071x over previous
//
#include <hip/hip_runtime.h>

#define N_NODES 100000
#define N_EDGES 3200000
#define R_REL   8
#define C_IN    128
#define HID     64
#define WCOLS   576   // 8 relations * 64 + 64 (root slot)
#define OFFMASK 0x03FFFFFFu

// counting-sort parameters
#define NBUCK 500     // dst buckets
#define NPB   200     // nodes per bucket (500*200 = N)
#define NBLK  256     // edge chunks (long runs: CHUNK/NBUCK = 25 edges = 100 B)
#define CHUNK 12500   // E / NBLK (exact)
#define NCELL (NBUCK * NBLK)   // 128000
#define BCAP  7680    // LDS staging capacity per bucket (mean 6400, sigma ~80)

typedef __attribute__((ext_vector_type(8))) short  short8;
typedef __attribute__((ext_vector_type(4))) float  float4v;

__device__ __forceinline__ float bf2f(unsigned short u) {
    union { unsigned int i; float f; } v; v.i = ((unsigned int)u) << 16; return v.f;
}
__device__ __forceinline__ unsigned short f2bf(float f) {
    union { float f; unsigned int i; } v; v.f = f;
    unsigned int r = v.i + 0x7FFFu + ((v.i >> 16) & 1u);   // RNE
    return (unsigned short)(r >> 16);
}
__device__ __forceinline__ float rl_f(float v, int j) {
    union { float f; int i; } a, b; a.f = v;
    b.i = __builtin_amdgcn_readlane(a.i, j);
    return b.f;
}

// ---------------- weight prep (f32 -> bf16, concatenated+transposed) ----------
__global__ void prep_wcat(const float* __restrict__ W1,
                          const float* __restrict__ root1,
                          const float* __restrict__ W2,
                          const float* __restrict__ root2,
                          unsigned short* __restrict__ BT1,
                          unsigned short* __restrict__ BT2) {
    int idx = blockIdx.x * 256 + threadIdx.x;
    const int T1 = WCOLS * C_IN;          // 73728
    const int T2 = WCOLS * HID;           // 36864
    if (idx < T1) {
        int c = idx / C_IN, k = idx % C_IN;
        float v;
        if (c < 512) { int r = c >> 6, h = c & 63; v = W1[r * (C_IN * 64) + k * 64 + h]; }
        else         { v = root1[k * 64 + (c - 512)]; }
        BT1[idx] = f2bf(v);
    } else if (idx < T1 + T2) {
        int j = idx - T1;
        int c = j / HID, k = j % HID;
        float v;
        if (c < 512) { int r = c >> 6, h = c & 63; v = W2[r * (HID * 64) + k * 64 + h]; }
        else         { v = root2[k * 64 + (c - 512)]; }
        BT2[j] = f2bf(v);
    }
}

// ---------------- K1: per-block LDS counting sort, sequential writes ---------
// esort[blk*CHUNK...] = block's edges sorted by bucket (packed src<<11|dl<<3|rel)
// bcountT[blk*NBUCK+b] = count; lstartT[blk*NBUCK+b] = local exclusive prefix.
__global__ __launch_bounds__(512)
void edge_sort_local(const int* __restrict__ src, const int* __restrict__ dst,
                     const int* __restrict__ et,
                     unsigned int* __restrict__ esort,
                     int* __restrict__ bcountT, int* __restrict__ lstartT) {
    __shared__ int cnt[NBUCK], cur[NBUCK], tsum[512];
    __shared__ unsigned int sedge[CHUNK];               // 50 KB
    const int blk = blockIdx.x, tid = threadIdx.x;
    const int e0 = blk * CHUNK;

    for (int i = tid; i < NBUCK; i += 512) cnt[i] = 0;
    __syncthreads();
    for (int i = tid; i < CHUNK; i += 512)
        atomicAdd(&cnt[dst[e0 + i] / NPB], 1);
    __syncthreads();

    // exclusive scan over 500 counters (1 per thread, Hillis-Steele over 512)
    int v = (tid < NBUCK) ? cnt[tid] : 0;
    tsum[tid] = v; __syncthreads();
    for (int off = 1; off < 512; off <<= 1) {
        int t = (tid >= off) ? tsum[tid - off] : 0;
        __syncthreads(); tsum[tid] += t; __syncthreads();
    }
    if (tid < NBUCK) cur[tid] = tsum[tid] - v;
    __syncthreads();

    for (int b = tid; b < NBUCK; b += 512) {
        bcountT[blk * NBUCK + b] = cnt[b];
        lstartT[blk * NBUCK + b] = cur[b];
    }
    __syncthreads();

    for (int i = tid; i < CHUNK; i += 512) {
        int d = dst[e0 + i];
        int b = d / NPB;
        int pos = atomicAdd(&cur[b], 1);
        sedge[pos] = ((unsigned int)src[e0 + i] << 11) |
                     ((unsigned int)(d - b * NPB) << 3) | (unsigned int)et[e0 + i];
    }
    __syncthreads();
    for (int i = tid; i < CHUNK; i += 512) esort[e0 + i] = sedge[i];
}

// ---------------- bucket totals + scan over 500 buckets ----------------------
__global__ __launch_bounds__(256)
void btot_sum(const int* __restrict__ bcountT, int* __restrict__ btot) {
    __shared__ int tsum[256];
    const int b = blockIdx.x, tid = threadIdx.x;
    int s = 0;
    for (int blk = tid; blk < NBLK; blk += 256) s += bcountT[blk * NBUCK + b];
    tsum[tid] = s; __syncthreads();
    for (int off = 128; off > 0; off >>= 1) {
        if (tid < off) tsum[tid] += tsum[tid + off];
        __syncthreads();
    }
    if (tid == 0) btot[b] = tsum[0];
}

__global__ __launch_bounds__(512)
void scan_btot(int* __restrict__ btot, int nb) {   // nb <= 512, exclusive in place
    __shared__ int tmp[512];
    int tid = threadIdx.x;
    int v = (tid < nb) ? btot[tid] : 0;
    tmp[tid] = v; __syncthreads();
    for (int off = 1; off < 512; off <<= 1) {
        int t = (tid >= off) ? tmp[tid - off] : 0;
        __syncthreads(); tmp[tid] += t; __syncthreads();
    }
    if (tid < nb) btot[tid] = tmp[tid] - v;
}

// ---------------- bucket_build v4: LDS-staged CSR emit, rowstart8 ------------
// one block per bucket. Emits elist (precomputed XW offsets) and the full
// per-(node,rel) boundary table rowstart8[n*8+r] — weights are derived in
// agg_fused from segment lengths, so welist is GONE (−12.8 MB write here,
// −12.8 MB read per agg dispatch, −37 KB LDS).
__global__ __launch_bounds__(512)
void bucket_build(const unsigned int* __restrict__ esort,
                  const int* __restrict__ bcountT, const int* __restrict__ lstartT,
                  const int* __restrict__ btot,
                  unsigned int* __restrict__ elist,
                  int* __restrict__ rowstart8) {
    __shared__ int   cnt[2048], cur[2048], tsum[512];   // 8192+8192+2048 B
    __shared__ int   rlen[NBLK], rpos[NBLK], rloff[NBLK]; // 3072 B
    __shared__ unsigned int sedge[BCAP];                // 30720 B
    __shared__ unsigned int selist[BCAP];               // 30720 B  (total ~83 KB)

    const int b = blockIdx.x, tid = threadIdx.x;
    const int seg0 = btot[b];

    for (int i = tid; i < 2048; i += 512) cnt[i] = 0;
    if (tid < NBLK) {
        rlen[tid] = bcountT[tid * NBUCK + b];
        rpos[tid] = tid * CHUNK + lstartT[tid * NBUCK + b];
    }
    __syncthreads();

    // ---- scan run lengths (1 run/thread, Hillis-Steele over 512) ----
    int rv = (tid < NBLK) ? rlen[tid] : 0;
    tsum[tid] = rv; __syncthreads();
    for (int off = 1; off < 512; off <<= 1) {
        int t = (tid >= off) ? tsum[tid - off] : 0;
        __syncthreads(); tsum[tid] += t; __syncthreads();
    }
    if (tid < NBLK) rloff[tid] = tsum[tid] - rv;
    const int total = tsum[NBLK - 1];       // bucket edge count
    __syncthreads();
    const bool fits = (total <= BCAP);      // safety fallback (mean 6400, 16 sigma margin)

    // ---- pass 1: flat stage + histogram (esort read once) ----
    for (int i = tid; i < total; i += 512) {
        int lo = 0, hi = NBLK - 1;          // largest blk with rloff[blk] <= i
        while (lo < hi) { int mid = (lo + hi + 1) >> 1; if (rloff[mid] <= i) lo = mid; else hi = mid - 1; }
        unsigned int e = esort[rpos[lo] + (i - rloff[lo])];
        if (fits) sedge[i] = e;
        atomicAdd(&cnt[(int)((e >> 3) & 255u) * 8 + (int)(e & 7u)], 1);
    }
    __syncthreads();

    // ---- exclusive scan over 2048 counters: 4/thread + Hillis-Steele ----
    int base = tid * 4, s = 0, loc[4];
#pragma unroll
    for (int k = 0; k < 4; ++k) { loc[k] = s; s += cnt[base + k]; }
    tsum[tid] = s; __syncthreads();
    for (int off = 1; off < 512; off <<= 1) {
        int t = (tid >= off) ? tsum[tid - off] : 0;
        __syncthreads(); tsum[tid] += t; __syncthreads();
    }
    int texcl = tsum[tid] - s;
#pragma unroll
    for (int k = 0; k < 4; ++k) cur[base + k] = texcl + loc[k];
    __syncthreads();

    // ---- per-(node,rel) boundary table (weights derived downstream) ----
    for (int i = tid; i < NPB * 8; i += 512)
        rowstart8[(b * NPB) * 8 + i] = seg0 + cur[i];
    if (b == NBUCK - 1 && tid == 0) rowstart8[N_NODES * 8] = N_EDGES;
    __syncthreads();

    // ---- pass 2: flat emit into LDS (scatter stays on-chip) ----
    for (int i = tid; i < total; i += 512) {
        unsigned int e;
        if (fits) e = sedge[i];
        else {
            int lo = 0, hi = NBLK - 1;
            while (lo < hi) { int mid = (lo + hi + 1) >> 1; if (rloff[mid] <= i) lo = mid; else hi = mid - 1; }
            e = esort[rpos[lo] + (i - rloff[lo])];
        }
        int r = (int)(e & 7u);
        int j = (int)((e >> 3) & 255u) * 8 + r;
        int p = atomicAdd(&cur[j], 1);
        unsigned int eo = (e >> 11) * WCOLS + (unsigned int)(r * 64);
        if (fits) selist[p] = eo;
        else      elist[seg0 + p] = eo;
    }
    __syncthreads();

    // ---- coalesced copy-out ----
    if (fits) {
        for (int i = tid; i < total; i += 512)
            elist[seg0 + i] = selist[i];
    }
}

// ---------------- GEMM: Out[N][576] (bf16) = A[N][K] @ Wcat ------------------
template <int K, bool AF32>
__global__ __launch_bounds__(256)
void gemm_rows(const void* __restrict__ Araw,
               const unsigned short* __restrict__ BT,
               unsigned short* __restrict__ Out, int nrows) {
    constexpr int KSTEPS = K / 32;
    constexpr int LDB = K + 8;
    __shared__ __align__(16) unsigned short Blds[64 * LDB];
    __shared__ __align__(16) unsigned short stage[4][16 * 64];

    const int wave = threadIdx.x >> 6;
    const int lane = threadIdx.x & 63;
    const int l15 = lane & 15, quad = lane >> 4;
    const int rowbase = blockIdx.x * 64 + wave * 16;
    int arow = rowbase + l15;
    if (arow >= nrows) arow = nrows - 1;

    short8 afrag[KSTEPS];
    if constexpr (AF32) {
        const float* Af = (const float*)Araw;
#pragma unroll
        for (int ks = 0; ks < KSTEPS; ++ks) {
            const float* p = Af + (size_t)arow * K + ks * 32 + quad * 8;
            float4v u0 = *(const float4v*)p;
            float4v u1 = *(const float4v*)(p + 4);
            short8 f;
            f[0] = (short)f2bf(u0[0]); f[1] = (short)f2bf(u0[1]);
            f[2] = (short)f2bf(u0[2]); f[3] = (short)f2bf(u0[3]);
            f[4] = (short)f2bf(u1[0]); f[5] = (short)f2bf(u1[1]);
            f[6] = (short)f2bf(u1[2]); f[7] = (short)f2bf(u1[3]);
            afrag[ks] = f;
        }
    } else {
        const unsigned short* Ab = (const unsigned short*)Araw;
#pragma unroll
        for (int ks = 0; ks < KSTEPS; ++ks)
            afrag[ks] = *(const short8*)(Ab + (size_t)arow * K + ks * 32 + quad * 8);
    }

    for (int chunk = 0; chunk < 9; ++chunk) {
        __syncthreads();
        {
            const unsigned short* src = BT + (size_t)chunk * 64 * K;
            const int nvec = 64 * K / 8;
            for (int i = threadIdx.x; i < nvec; i += 256) {
                int r = i / (K / 8);
                int cpos = (i % (K / 8)) * 8;
                *(uint4*)(&Blds[r * LDB + cpos]) = *(const uint4*)(src + r * K + cpos);
            }
        }
        __syncthreads();

        float4v acc[4];
#pragma unroll
        for (int ct = 0; ct < 4; ++ct) { acc[ct][0] = 0.f; acc[ct][1] = 0.f; acc[ct][2] = 0.f; acc[ct][3] = 0.f; }

#pragma unroll
        for (int ct = 0; ct < 4; ++ct) {
#pragma unroll
            for (int ks = 0; ks < KSTEPS; ++ks) {
                short8 bfrag = *(const short8*)(&Blds[(ct * 16 + l15) * LDB + ks * 32 + quad * 8]);
                acc[ct] = __builtin_amdgcn_mfma_f32_16x16x32_bf16(afrag[ks], bfrag, acc[ct], 0, 0, 0);
            }
        }

#pragma unroll
        for (int ct = 0; ct < 4; ++ct)
#pragma unroll
            for (int r = 0; r < 4; ++r)
                stage[wave][(quad * 4 + r) * 64 + ct * 16 + l15] = f2bf(acc[ct][r]);
        __syncthreads();

        {
            int r = lane >> 2, j = lane & 3;
            int orow = rowbase + r;
            if (orow < nrows) {
#pragma unroll
                for (int p = 0; p < 2; ++p) {
                    int c0 = (j + p * 4) * 8;
                    uint4 v = *(const uint4*)&stage[wave][r * 64 + c0];
                    *(uint4*)(Out + (size_t)orow * WCOLS + chunk * 64 + c0) = v;
                }
            }
        }
    }
}

// ---------------- fused CSR aggregate + root + bias (+relu) ------------------
// one wave per node, lane = channel. 16-deep explicit gather pipeline.
// Weights derived from per-(node,rel) segment boundaries (rowstart8) —
// no welist stream.
template <int MODE>   // 0: relu -> bf16 h ; 1: -> f32 out
__global__ __launch_bounds__(256)
void agg_fused(const unsigned short* __restrict__ XW,
               const unsigned int* __restrict__ elist,
               const int* __restrict__ rowstart8,
               const float* __restrict__ bias,
               void* __restrict__ outp) {
    const int wave = threadIdx.x >> 6, lane = threadIdx.x & 63;
    const int n = blockIdx.x * 4 + wave;          // grid covers N exactly
    int r9 = 0;
    if (lane < 9) r9 = rowstart8[n * 8 + lane];
    const int b0 = __builtin_amdgcn_readlane(r9, 0);
    const int b1 = __builtin_amdgcn_readlane(r9, 1);
    const int b2 = __builtin_amdgcn_readlane(r9, 2);
    const int b3 = __builtin_amdgcn_readlane(r9, 3);
    const int b4 = __builtin_amdgcn_readlane(r9, 4);
    const int b5 = __builtin_amdgcn_readlane(r9, 5);
    const int b6 = __builtin_amdgcn_readlane(r9, 6);
    const int b7 = __builtin_amdgcn_readlane(r9, 7);
    const int b8 = __builtin_amdgcn_readlane(r9, 8);
    const int beg = b0, end = b8;

    // inverse segment lengths (uniform across wave)
    auto invlen = [](int a, int bnd) {
        int l = bnd - a; return 1.0f / (float)(l > 1 ? l : 1);
    };
    const float il0 = invlen(b0, b1), il1 = invlen(b1, b2);
    const float il2 = invlen(b2, b3), il3 = invlen(b3, b4);
    const float il4 = invlen(b4, b5), il5 = invlen(b5, b6);
    const float il6 = invlen(b6, b7), il7 = invlen(b7, b8);

    const unsigned short* XWl = XW + lane;        // fold lane offset into base

    float acc = 0.f;
    int i = beg;
    while (i < end) {
        int m = end - i; if (m > 64) m = 64;
        int idx = i + lane; if (idx >= end) idx = end - 1;
        unsigned int ub = elist[idx];             // one coalesced load / 64 edges
        // per-lane weight from segment membership (cmp+sel chain, ~15 VALU/chunk)
        float wb = il0;
        wb = (idx >= b1) ? il1 : wb;
        wb = (idx >= b2) ? il2 : wb;
        wb = (idx >= b3) ? il3 : wb;
        wb = (idx >= b4) ? il4 : wb;
        wb = (idx >= b5) ? il5 : wb;
        wb = (idx >= b6) ? il6 : wb;
        wb = (idx >= b7) ? il7 : wb;

        int j = 0;
        for (; j + 16 <= m; j += 16) {
            float vv[16], ww[16];
#pragma unroll
            for (int t = 0; t < 16; ++t) {
                unsigned int u = (unsigned int)__builtin_amdgcn_readlane((int)ub, j + t) & OFFMASK;
                ww[t] = rl_f(wb, j + t);
                vv[t] = bf2f(XWl[u]);
            }
#pragma unroll
            for (int t = 0; t < 16; ++t) acc += ww[t] * vv[t];
        }
        for (; j + 4 <= m; j += 4) {
            float vv[4], ww[4];
#pragma unroll
            for (int t = 0; t < 4; ++t) {
                unsigned int u = (unsigned int)__builtin_amdgcn_readlane((int)ub, j + t) & OFFMASK;
                ww[t] = rl_f(wb, j + t);
                vv[t] = bf2f(XWl[u]);
            }
#pragma unroll
            for (int t = 0; t < 4; ++t) acc += ww[t] * vv[t];
        }
        for (; j < m; ++j) {
            unsigned int u = (unsigned int)__builtin_amdgcn_readlane((int)ub, j) & OFFMASK;
            float w = rl_f(wb, j);
            acc += w * bf2f(XWl[u]);
        }
        i += m;
    }

    float res = acc + bf2f(XW[(size_t)n * WCOLS + 512 + lane]) + bias[lane];
    if (MODE == 0) {
        res = res > 0.f ? res : 0.f;
        ((unsigned short*)outp)[(size_t)n * 64 + lane] = f2bf(res);
    } else {
        ((float*)outp)[(size_t)n * 64 + lane] = res;
    }
}

// ---------------- launch ------------------------------------------------------
extern "C" void kernel_launch(void* const* d_in, const int* in_sizes, int n_in,
                              void* d_out, int out_size, void* d_ws, size_t ws_size,
                              hipStream_t stream) {
    const float* x     = (const float*)d_in[0];
    const int*   eidx  = (const int*)d_in[1];
    const int*   etyp  = (const int*)d_in[2];
    const float* W1    = (const float*)d_in[3];
    const float* root1 = (const float*)d_in[4];
    const float* b1    = (const float*)d_in[5];
    const float* W2    = (const float*)d_in[6];
    const float* root2 = (const float*)d_in[7];
    const float* b2    = (const float*)d_in[8];
    float*       out   = (float*)d_out;

    char* ws = (char*)d_ws;
    size_t off = 0;
    auto alloc = [&](size_t bytes) { char* p = ws + off; off += (bytes + 255) & ~(size_t)255; return p; };

    unsigned short* xW       = (unsigned short*)alloc((size_t)N_NODES * WCOLS * 2); // 115.2 MB (reused as hW)
    unsigned short* h        = (unsigned short*)alloc((size_t)N_NODES * HID * 2);   //  12.8 MB
    unsigned int*   elist    = (unsigned int*)alloc((size_t)N_EDGES * 4);           //  12.8 MB
    int*            rowstart8= (int*)alloc(((size_t)N_NODES * 8 + 1) * 4);          //   3.2 MB
    unsigned short* BT1      = (unsigned short*)alloc((size_t)WCOLS * C_IN * 2);
    unsigned short* BT2      = (unsigned short*)alloc((size_t)WCOLS * HID * 2);
    // total ~144.5 MB

    // sort scratch aliases into xW (dead before gemm1 writes xW)
    unsigned int* esort   = (unsigned int*)xW;                          // 12.8 MB
    int*          bcountT = (int*)((char*)xW + (size_t)N_EDGES * 4);    //  0.5 MB
    int*          lstartT = bcountT + NCELL;                            //  0.5 MB
    int*          btot    = lstartT + NCELL;                            //  2 KB

    const int* srcp = eidx;
    const int* dstp = eidx + N_EDGES;

    prep_wcat<<<(WCOLS * (C_IN + HID) + 255) / 256, 256, 0, stream>>>(W1, root1, W2, root2, BT1, BT2);

    // CSR build — sequential-write sort + fused per-bucket CSR emit
    edge_sort_local<<<NBLK, 512, 0, stream>>>(srcp, dstp, etyp, esort, bcountT, lstartT);
    btot_sum<<<NBUCK, 256, 0, stream>>>(bcountT, btot);
    scan_btot<<<1, 512, 0, stream>>>(btot, NBUCK);
    bucket_build<<<NBUCK, 512, 0, stream>>>(esort, bcountT, lstartT, btot, elist, rowstart8);

    const int gemm_grid = (N_NODES + 63) / 64;    // 1563
    const int agg_grid  = N_NODES / 4;            // 25000

    // layer 1: x (f32) -> xW (bf16) -> h (bf16, relu)
    gemm_rows<C_IN, true><<<gemm_grid, 256, 0, stream>>>((const void*)x, BT1, xW, N_NODES);
    agg_fused<0><<<agg_grid, 256, 0, stream>>>(xW, elist, rowstart8, b1, (void*)h);

    // layer 2: h -> hW (reuse xW) -> out (f32)
    gemm_rows<HID, false><<<gemm_grid, 256, 0, stream>>>((const void*)h, BT2, xW, N_NODES);
    agg_fused<1><<<agg_grid, 256, 0, stream>>>(xW, elist, rowstart8, b2, (void*)out);
}